// Round 1
// baseline (292.997 us; speedup 1.0000x reference)
//
#include <hip/hip_runtime.h>

// BiAttention: B=16, M=N=512, V=A=1024.
//   s_q = relu(q @ W1^T)  [B*M, A]
//   s_p = relu(p @ W2^T)  [B*N, A]
//   s   = s_q @ s_p^T     [B, M, N]   (batched)
//   wp  = softmax_n(s) (p_mask), wq = softmax_m(s^T) (q_mask)
//   out_q = wp @ p, out_p = wq @ q   -> d_out = [out_p | out_q]
//
// Precision: projections + score GEMM use 3-term bf16 split (hi/lo) MFMA
// (~fp32 accuracy); output GEMMs are plain bf16 MFMA.
//
// Workspace layout (requires ws_size >= 100,663,296 B = 96 MiB):
//   [0,32M)    s_q fp32   -- reused later as st (s transposed, 16M)
//   [32M,64M)  s_p fp32   -- reused later as pT bf16 (16M) + qT bf16 (16M)
//   [64M,80M)  s   fp32
//   [80M,88M)  wp  bf16
//   [88M,96M)  wq  bf16

#define B_DIM 16
#define M_SEQ 512
#define N_SEQ 512
#define V_DIM 1024
#define A_DIM 1024

typedef __attribute__((ext_vector_type(8))) short bf16x8;
typedef __attribute__((ext_vector_type(4))) float f32x4;

__device__ __forceinline__ short f2bf(float x) {
  union { float f; unsigned u; } v; v.f = x;
  unsigned r = v.u + 0x7fffu + ((v.u >> 16) & 1u);
  return (short)(r >> 16);
}
__device__ __forceinline__ float bf2f(short s) {
  union { unsigned u; float f; } v; v.u = ((unsigned)(unsigned short)s) << 16;
  return v.f;
}
__device__ __forceinline__ void split1(float x, short& h, short& l) {
  h = f2bf(x);
  l = f2bf(x - bf2f(h));
}

// ---------------- NT GEMM, fp32 inputs, on-the-fly hi/lo split, 3-term MFMA
// C[m,n] = (relu?) sum_k A[m,k]*B[n,k].  M,N multiples of 128, K multiple of 32.
template<bool RELU>
__global__ __launch_bounds__(256) void gemm_nt_split(
    const float* __restrict__ A, const float* __restrict__ B, float* __restrict__ C,
    int K, int lda, int ldb, int ldc, long sA, long sB, long sC)
{
  constexpr int LDST = 40;  // bf16 row stride: 80B -> rows 0..7 tile all 32 banks
  __shared__ short Ah[128 * LDST], Al[128 * LDST], Bh[128 * LDST], Bl[128 * LDST];

  const float* Ab = A + (long)blockIdx.z * sA;
  const float* Bb = B + (long)blockIdx.z * sB;
  float* Cb = C + (long)blockIdx.z * sC;
  const int m0 = blockIdx.y * 128, n0 = blockIdx.x * 128;
  const int tid = threadIdx.x;
  const int lane = tid & 63, wave = tid >> 6;
  const int wr = wave >> 1, wc = wave & 1;
  const int lrow = lane & 15, koff = (lane >> 4) << 3;

  f32x4 acc[4][4] = {};

  for (int k0 = 0; k0 < K; k0 += 32) {
    __syncthreads();
#pragma unroll
    for (int r = 0; r < 4; ++r) {
      int id = (r << 8) + tid;
      int row = id >> 3, c4 = (id & 7) << 2;
      float4 va = *reinterpret_cast<const float4*>(Ab + (long)(m0 + row) * lda + k0 + c4);
      float4 vb = *reinterpret_cast<const float4*>(Bb + (long)(n0 + row) * ldb + k0 + c4);
      short4 ha, la, hb, lb;
      split1(va.x, ha.x, la.x); split1(va.y, ha.y, la.y);
      split1(va.z, ha.z, la.z); split1(va.w, ha.w, la.w);
      split1(vb.x, hb.x, lb.x); split1(vb.y, hb.y, lb.y);
      split1(vb.z, hb.z, lb.z); split1(vb.w, hb.w, lb.w);
      int o = row * LDST + c4;
      *reinterpret_cast<short4*>(&Ah[o]) = ha;
      *reinterpret_cast<short4*>(&Al[o]) = la;
      *reinterpret_cast<short4*>(&Bh[o]) = hb;
      *reinterpret_cast<short4*>(&Bl[o]) = lb;
    }
    __syncthreads();

    bf16x8 ah[4], al[4], bh[4], bl[4];
#pragma unroll
    for (int i = 0; i < 4; ++i) {
      int ao = (wr * 64 + i * 16 + lrow) * LDST + koff;
      int bo = (wc * 64 + i * 16 + lrow) * LDST + koff;
      ah[i] = *reinterpret_cast<const bf16x8*>(&Ah[ao]);
      al[i] = *reinterpret_cast<const bf16x8*>(&Al[ao]);
      bh[i] = *reinterpret_cast<const bf16x8*>(&Bh[bo]);
      bl[i] = *reinterpret_cast<const bf16x8*>(&Bl[bo]);
    }
#pragma unroll
    for (int mi = 0; mi < 4; ++mi)
#pragma unroll
      for (int ni = 0; ni < 4; ++ni) {
        acc[mi][ni] = __builtin_amdgcn_mfma_f32_16x16x32_bf16(ah[mi], bh[ni], acc[mi][ni], 0, 0, 0);
        acc[mi][ni] = __builtin_amdgcn_mfma_f32_16x16x32_bf16(ah[mi], bl[ni], acc[mi][ni], 0, 0, 0);
        acc[mi][ni] = __builtin_amdgcn_mfma_f32_16x16x32_bf16(al[mi], bh[ni], acc[mi][ni], 0, 0, 0);
      }
  }

  const int rb = m0 + wr * 64 + ((lane >> 4) << 2);
  const int cb = n0 + wc * 64 + (lane & 15);
#pragma unroll
  for (int mi = 0; mi < 4; ++mi)
#pragma unroll
    for (int ni = 0; ni < 4; ++ni)
#pragma unroll
      for (int r2 = 0; r2 < 4; ++r2) {
        float x = acc[mi][ni][r2];
        if (RELU) x = fmaxf(x, 0.0f);
        Cb[(long)(rb + mi * 16 + r2) * ldc + cb + ni * 16] = x;
      }
}

// ---------------- NT GEMM, bf16 inputs (1-term), fp32 out -----------------
__global__ __launch_bounds__(256) void gemm_nt_bf16(
    const short* __restrict__ A, const short* __restrict__ B, float* __restrict__ C,
    int K, int lda, int ldb, int ldc, long sA, long sB, long sC)
{
  constexpr int LDST = 40;
  __shared__ short As[128 * LDST], Bs[128 * LDST];

  const short* Ab = A + (long)blockIdx.z * sA;
  const short* Bb = B + (long)blockIdx.z * sB;
  float* Cb = C + (long)blockIdx.z * sC;
  const int m0 = blockIdx.y * 128, n0 = blockIdx.x * 128;
  const int tid = threadIdx.x;
  const int lane = tid & 63, wave = tid >> 6;
  const int wr = wave >> 1, wc = wave & 1;
  const int lrow = lane & 15, koff = (lane >> 4) << 3;

  f32x4 acc[4][4] = {};

  for (int k0 = 0; k0 < K; k0 += 32) {
    __syncthreads();
#pragma unroll
    for (int r = 0; r < 2; ++r) {
      int id = (r << 8) + tid;
      int row = id >> 2, c8 = (id & 3) << 3;
      int4 va = *reinterpret_cast<const int4*>(Ab + (long)(m0 + row) * lda + k0 + c8);
      int4 vb = *reinterpret_cast<const int4*>(Bb + (long)(n0 + row) * ldb + k0 + c8);
      int o = row * LDST + c8;
      *reinterpret_cast<int4*>(&As[o]) = va;
      *reinterpret_cast<int4*>(&Bs[o]) = vb;
    }
    __syncthreads();

    bf16x8 a[4], b[4];
#pragma unroll
    for (int i = 0; i < 4; ++i) {
      a[i] = *reinterpret_cast<const bf16x8*>(&As[(wr * 64 + i * 16 + lrow) * LDST + koff]);
      b[i] = *reinterpret_cast<const bf16x8*>(&Bs[(wc * 64 + i * 16 + lrow) * LDST + koff]);
    }
#pragma unroll
    for (int mi = 0; mi < 4; ++mi)
#pragma unroll
      for (int ni = 0; ni < 4; ++ni)
        acc[mi][ni] = __builtin_amdgcn_mfma_f32_16x16x32_bf16(a[mi], b[ni], acc[mi][ni], 0, 0, 0);
  }

  const int rb = m0 + wr * 64 + ((lane >> 4) << 2);
  const int cb = n0 + wc * 64 + (lane & 15);
#pragma unroll
  for (int mi = 0; mi < 4; ++mi)
#pragma unroll
    for (int ni = 0; ni < 4; ++ni)
#pragma unroll
      for (int r2 = 0; r2 < 4; ++r2)
        Cb[(long)(rb + mi * 16 + r2) * ldc + cb + ni * 16] = acc[mi][ni][r2];
}

// ---------------- row softmax (cols == 512), bf16 weights out -------------
__global__ __launch_bounds__(256) void softmax_row(
    const float* __restrict__ S, const int* __restrict__ mask, short* __restrict__ W)
{
  const int row = blockIdx.x;          // b*512 + r
  const int b = row >> 9;
  const float* Sr = S + (long)row * 512;
  const int* mr = mask + (long)b * 512;
  const int tid = threadIdx.x;
  const int lane = tid & 63, wave = tid >> 6;
  __shared__ float red[4];

  float v0 = mr[tid] ? Sr[tid] : -1e30f;
  float v1 = mr[tid + 256] ? Sr[tid + 256] : -1e30f;
  float mx = fmaxf(v0, v1);
#pragma unroll
  for (int o = 32; o >= 1; o >>= 1) mx = fmaxf(mx, __shfl_xor(mx, o, 64));
  if (lane == 0) red[wave] = mx;
  __syncthreads();
  mx = fmaxf(fmaxf(red[0], red[1]), fmaxf(red[2], red[3]));
  __syncthreads();
  float e0 = __expf(v0 - mx), e1 = __expf(v1 - mx);
  float sm = e0 + e1;
#pragma unroll
  for (int o = 32; o >= 1; o >>= 1) sm += __shfl_xor(sm, o, 64);
  if (lane == 0) red[wave] = sm;
  __syncthreads();
  float inv = 1.0f / (red[0] + red[1] + red[2] + red[3]);
  W[(long)row * 512 + tid] = f2bf(e0 * inv);
  W[(long)row * 512 + tid + 256] = f2bf(e1 * inv);
}

// ---------------- 32x32 tiled transposes ----------------------------------
__global__ __launch_bounds__(256) void transpose_f32(
    const float* __restrict__ src, float* __restrict__ dst, int R, int Ccols)
{
  __shared__ float t[32][33];
  const long bo = (long)blockIdx.z * R * Ccols;
  const int c0 = blockIdx.x * 32, r0 = blockIdx.y * 32;
  const int tx = threadIdx.x, ty = threadIdx.y;
#pragma unroll
  for (int j = 0; j < 4; ++j) {
    int rr = ty + j * 8;
    t[rr][tx] = src[bo + (long)(r0 + rr) * Ccols + c0 + tx];
  }
  __syncthreads();
#pragma unroll
  for (int j = 0; j < 4; ++j) {
    int rr = ty + j * 8;
    dst[bo + (long)(c0 + rr) * R + r0 + tx] = t[tx][rr];
  }
}

__global__ __launch_bounds__(256) void transpose_cvt(
    const float* __restrict__ src, short* __restrict__ dst, int R, int Ccols)
{
  __shared__ float t[32][33];
  const long bo = (long)blockIdx.z * R * Ccols;
  const int c0 = blockIdx.x * 32, r0 = blockIdx.y * 32;
  const int tx = threadIdx.x, ty = threadIdx.y;
#pragma unroll
  for (int j = 0; j < 4; ++j) {
    int rr = ty + j * 8;
    t[rr][tx] = src[bo + (long)(r0 + rr) * Ccols + c0 + tx];
  }
  __syncthreads();
#pragma unroll
  for (int j = 0; j < 4; ++j) {
    int rr = ty + j * 8;
    dst[bo + (long)(c0 + rr) * R + r0 + tx] = f2bf(t[tx][rr]);
  }
}

extern "C" void kernel_launch(void* const* d_in, const int* in_sizes, int n_in,
                              void* d_out, int out_size, void* d_ws, size_t ws_size,
                              hipStream_t stream) {
  const float* q = (const float*)d_in[0];
  const float* p = (const float*)d_in[1];
  const int* q_mask = (const int*)d_in[2];
  const int* p_mask = (const int*)d_in[3];
  const float* W1 = (const float*)d_in[4];
  const float* W2 = (const float*)d_in[5];
  float* out_p = (float*)d_out;
  float* out_q = out_p + (size_t)B_DIM * N_SEQ * V_DIM;

  char* ws = (char*)d_ws;
  float* s_q = (float*)ws;                         // 33,554,432 B
  float* s_p = (float*)(ws + 33554432);            // 33,554,432 B
  float* s   = (float*)(ws + 67108864);            // 16,777,216 B
  short* wp  = (short*)(ws + 83886080);            //  8,388,608 B
  short* wq  = (short*)(ws + 92274688);            //  8,388,608 B
  float* st  = s_q;                                // reuse (s_q dead after s)
  short* pT  = (short*)s_p;                        // reuse (s_p dead after s)
  short* qT  = (short*)(ws + 33554432 + 16777216);

  dim3 blk(256);

  // Projections: [8192,1024] = relu([8192,1024] @ [1024,1024]^T), split MFMA
  gemm_nt_split<true><<<dim3(A_DIM / 128, (B_DIM * M_SEQ) / 128, 1), blk, 0, stream>>>(
      q, W1, s_q, V_DIM, V_DIM, V_DIM, A_DIM, 0, 0, 0);
  gemm_nt_split<true><<<dim3(A_DIM / 128, (B_DIM * N_SEQ) / 128, 1), blk, 0, stream>>>(
      p, W2, s_p, V_DIM, V_DIM, V_DIM, A_DIM, 0, 0, 0);

  // Scores: s[b] = s_q[b] @ s_p[b]^T  (512x512, K=1024), split MFMA
  gemm_nt_split<false><<<dim3(N_SEQ / 128, M_SEQ / 128, B_DIM), blk, 0, stream>>>(
      s_q, s_p, s, A_DIM, A_DIM, A_DIM, N_SEQ,
      (long)M_SEQ * A_DIM, (long)N_SEQ * A_DIM, (long)M_SEQ * N_SEQ);

  // s^T for the other softmax direction (overwrites s_q region)
  transpose_f32<<<dim3(N_SEQ / 32, M_SEQ / 32, B_DIM), dim3(32, 8), 0, stream>>>(
      s, st, M_SEQ, N_SEQ);

  // Softmaxes -> bf16 weights
  softmax_row<<<dim3(B_DIM * M_SEQ), blk, 0, stream>>>(s, p_mask, wp);
  softmax_row<<<dim3(B_DIM * N_SEQ), blk, 0, stream>>>(st, q_mask, wq);

  // p^T, q^T as bf16 (overwrites s_p region)
  transpose_cvt<<<dim3(V_DIM / 32, N_SEQ / 32, B_DIM), dim3(32, 8), 0, stream>>>(
      p, pT, N_SEQ, V_DIM);
  transpose_cvt<<<dim3(V_DIM / 32, M_SEQ / 32, B_DIM), dim3(32, 8), 0, stream>>>(
      q, qT, M_SEQ, V_DIM);

  // out_q[b] = wp[b] @ pT[b]^T   ([512,512] x [1024,512]^T -> [512,1024])
  gemm_nt_bf16<<<dim3(V_DIM / 128, M_SEQ / 128, B_DIM), blk, 0, stream>>>(
      wp, pT, out_q, N_SEQ, N_SEQ, N_SEQ, V_DIM,
      (long)M_SEQ * N_SEQ, (long)V_DIM * N_SEQ, (long)M_SEQ * V_DIM);
  // out_p[b] = wq[b] @ qT[b]^T
  gemm_nt_bf16<<<dim3(V_DIM / 128, N_SEQ / 128, B_DIM), blk, 0, stream>>>(
      wq, qT, out_p, M_SEQ, M_SEQ, M_SEQ, V_DIM,
      (long)N_SEQ * M_SEQ, (long)V_DIM * M_SEQ, (long)N_SEQ * V_DIM);
}

// Round 2
// 231.248 us; speedup vs baseline: 1.2670x; 1.2670x over previous
//
#include <hip/hip_runtime.h>

// BiAttention: B=16, M=N=512, V=A=1024, all-fp16 MFMA pipeline.
//   s_q = relu(q @ W1^T), s_p = relu(p @ W2^T)        [fp16 2-term split GEMM]
//   s   = s_q @ s_p^T (batched)                        [fp16 2-term split GEMM]
//   wp  = softmax_n(s), wq = softmax_m(s^T)
//   out_q = wp @ p, out_p = wq @ q                     [fp16 1-term GEMM]
//
// Precision: x = xh + xl (fp16 split) on the A side; B side single fp16.
// (ah+al)*bh == a*bh exactly; error = only B's 2^-11 rounding.
//
// All fp16 GEMM operands live in a TILED+SWIZZLED global layout:
//   tiles of 128x64, elem (r,k) at tile[(r&127)*64 + ((k&63) ^ ((r&7)<<3))]
// so the GEMM stages tiles linearly with global_load_lds(16B) and
// ds_read_b128 hits ~conflict-free banks.
//
// Workspace (92 MiB used):
//   [0,2)   W1h    [2,4)  W2h
//   [4,20)  xh     [20,36) xl        (q splits, then p splits)
//   [36,52) s_q_h  [52,68) s_q_l     [68,84) s_p_h
//   -- after projections (x dead):      s   fp32 [4,20)
//   -- after scores (sq/sp dead):       st  fp32 [20,36), wq [68,76), wp [84,92)
//                                       pT [36,52), qT [52,68)

#define B_DIM 16
#define M_SEQ 512
#define V_DIM 1024

typedef _Float16 f16x8 __attribute__((ext_vector_type(8)));
typedef float f32x4 __attribute__((ext_vector_type(4)));

__device__ __forceinline__ long swzi(int r, int k, int ktiles) {
  return ((long)((r >> 7) * ktiles + (k >> 6)) << 13)
       + ((r & 127) << 6) + ((k & 63) ^ ((r & 7) << 3));
}

// ---- fp32 -> fp16 hi(/lo) split into tiled-swizzled layout, K=1024 -------
__global__ __launch_bounds__(256) void split_f16_swz(
    const float* __restrict__ src, _Float16* __restrict__ h, _Float16* __restrict__ l)
{
  long g = (long)blockIdx.x * 256 + threadIdx.x;   // one thread per 8 elems
  int r = (int)(g >> 7);                           // 1024/8 = 128 chunks/row
  int c8 = ((int)g & 127) << 3;
  const float* s = src + ((long)r << 10) + c8;
  long o = swzi(r, c8, 16);
  f16x8 hh, ll;
#pragma unroll
  for (int i = 0; i < 8; ++i) {
    float x = s[i];
    _Float16 hv = (_Float16)x;
    hh[i] = hv;
    ll[i] = (_Float16)(x - (float)hv);
  }
  *(f16x8*)(h + o) = hh;
  if (l != nullptr) *(f16x8*)(l + o) = ll;
}

// ---- unified NT GEMM on swizzled fp16 tiles -------------------------------
// NTERMS=2: A = [Ah | Al] along K (K_eff = 2K), B = [Bh | Bh].
// OUTMODE: 0 = fp32 row-major; 1 = fp16 swizzled hi; 2 = fp16 swizzled hi+lo.
template<int NTERMS, bool RELU, int OUTMODE>
__global__ __launch_bounds__(256, 2) void gemm_swz(
    const _Float16* __restrict__ Ah, const _Float16* __restrict__ Al,
    const _Float16* __restrict__ Bh,
    float* __restrict__ Cf, _Float16* __restrict__ Ch, _Float16* __restrict__ Cl,
    const int ktr, const int ldc,
    const long aBatchTiles, const long bBatchTiles, const long cBatchElems,
    const int cTilesRow)
{
  __shared__ _Float16 sA[2][8192], sB[2][8192];

  // XCD-chunked block swizzle (nwg % 8 == 0 for all our grids)
  const int gx = gridDim.x, gy = gridDim.y;
  long nwg = (long)gx * gy * gridDim.z;
  long bid = blockIdx.x + (long)gx * (blockIdx.y + (long)gy * blockIdx.z);
  long chunk = nwg >> 3;
  long o = (bid & 7) * chunk + (bid >> 3);
  const int bx = (int)(o % gx);
  const int by = (int)((o / gx) % gy);
  const int bz = (int)(o / ((long)gx * gy));

  const int tid = threadIdx.x;
  const int lane = tid & 63, wave = tid >> 6;
  const int wr = wave >> 1, wc = wave & 1;
  const int lrow = lane & 15;
  const int kb = (lane >> 4) << 4;        // byte offset of 8-elem group in 32-k window
  const int sw = (lrow & 7) << 4;         // byte XOR swizzle for this lane's rows

  const long aRow = (long)bz * aBatchTiles + (long)by * ktr;
  const long bRow = (long)bz * bBatchTiles + (long)bx * ktr;
  const int NT = NTERMS * ktr;

  f32x4 acc[4][4] = {};

  auto stage = [&](int buf, int t) {
    int kt = t;
    const _Float16* As = Ah;
    if (NTERMS == 2 && t >= ktr) { As = Al; kt = t - ktr; }
    const _Float16* ga = As + ((aRow + kt) << 13) + tid * 8;
    const _Float16* gb = Bh + ((bRow + kt) << 13) + tid * 8;
    _Float16* la = &sA[buf][(tid & 192) * 8];
    _Float16* lb = &sB[buf][(tid & 192) * 8];
#pragma unroll
    for (int j = 0; j < 4; ++j) {
      __builtin_amdgcn_global_load_lds(
          (const __attribute__((address_space(1))) void*)(ga + j * 2048),
          (__attribute__((address_space(3))) void*)(la + j * 2048), 16, 0, 0);
      __builtin_amdgcn_global_load_lds(
          (const __attribute__((address_space(1))) void*)(gb + j * 2048),
          (__attribute__((address_space(3))) void*)(lb + j * 2048), 16, 0, 0);
    }
  };

  auto compute = [&](int buf) {
    const char* baseA = (const char*)&sA[buf][0] + (wr * 64 + lrow) * 128;
    const char* baseB = (const char*)&sB[buf][0] + (wc * 64 + lrow) * 128;
#pragma unroll
    for (int ks = 0; ks < 2; ++ks) {
      const int cb = (ks * 64 + kb) ^ sw;
      f16x8 a[4], b[4];
#pragma unroll
      for (int i = 0; i < 4; ++i) {
        a[i] = *(const f16x8*)(baseA + i * 2048 + cb);
        b[i] = *(const f16x8*)(baseB + i * 2048 + cb);
      }
#pragma unroll
      for (int mi = 0; mi < 4; ++mi)
#pragma unroll
        for (int ni = 0; ni < 4; ++ni)
          acc[mi][ni] = __builtin_amdgcn_mfma_f32_16x16x32_f16(a[mi], b[ni], acc[mi][ni], 0, 0, 0);
    }
  };

  stage(0, 0);
  int cur = 0;
  for (int t = 0; t < NT; ++t) {
    if (t + 1 < NT) {
      stage(cur ^ 1, t + 1);
      asm volatile("s_waitcnt vmcnt(8)" ::: "memory");   // drain tile t, keep t+1 in flight
    } else {
      asm volatile("s_waitcnt vmcnt(0)" ::: "memory");
    }
    __syncthreads();
    compute(cur);
    __syncthreads();
    cur ^= 1;
  }

  const int r0 = by * 128 + wr * 64 + ((lane >> 4) << 2);
  const int c0 = bx * 128 + wc * 64 + (lane & 15);
  if (OUTMODE == 0) {
    float* Cb = Cf + (long)bz * cBatchElems;
#pragma unroll
    for (int mi = 0; mi < 4; ++mi)
#pragma unroll
      for (int ni = 0; ni < 4; ++ni)
#pragma unroll
        for (int r2 = 0; r2 < 4; ++r2)
          Cb[(long)(r0 + mi * 16 + r2) * ldc + c0 + ni * 16] = acc[mi][ni][r2];
  } else {
#pragma unroll
    for (int mi = 0; mi < 4; ++mi)
#pragma unroll
      for (int ni = 0; ni < 4; ++ni)
#pragma unroll
        for (int r2 = 0; r2 < 4; ++r2) {
          int r = r0 + mi * 16 + r2, c = c0 + ni * 16;
          float x = acc[mi][ni][r2];
          if (RELU) x = fmaxf(x, 0.0f);
          long idx = (long)bz * cBatchElems
                   + ((long)((r >> 7) * cTilesRow + (c >> 6)) << 13)
                   + ((r & 127) << 6) + ((c & 63) ^ ((r & 7) << 3));
          _Float16 hv = (_Float16)x;
          Ch[idx] = hv;
          if (OUTMODE == 2) Cl[idx] = (_Float16)(x - (float)hv);
        }
  }
}

// ---- row softmax (512 cols), fp16 swizzled weights out (kdim=512) --------
__global__ __launch_bounds__(256) void softmax_swz(
    const float* __restrict__ S, const int* __restrict__ mask, _Float16* __restrict__ W)
{
  const int row = blockIdx.x;              // b*512 + m
  const int b = row >> 9, m = row & 511;
  const float* Sr = S + (long)row * 512;
  const int* mr = mask + (long)b * 512;
  const int tid = threadIdx.x;
  const int lane = tid & 63, wave = tid >> 6;
  __shared__ float red[4];

  float v0 = mr[tid] ? Sr[tid] : -1e30f;
  float v1 = mr[tid + 256] ? Sr[tid + 256] : -1e30f;
  float mx = fmaxf(v0, v1);
#pragma unroll
  for (int of = 32; of >= 1; of >>= 1) mx = fmaxf(mx, __shfl_xor(mx, of, 64));
  if (lane == 0) red[wave] = mx;
  __syncthreads();
  mx = fmaxf(fmaxf(red[0], red[1]), fmaxf(red[2], red[3]));
  __syncthreads();
  float e0 = __expf(v0 - mx), e1 = __expf(v1 - mx);
  float sm = e0 + e1;
#pragma unroll
  for (int of = 32; of >= 1; of >>= 1) sm += __shfl_xor(sm, of, 64);
  if (lane == 0) red[wave] = sm;
  __syncthreads();
  float inv = 1.0f / (red[0] + red[1] + red[2] + red[3]);

  long base = (long)b * 262144 + ((long)((m >> 7) * 8) << 13) + ((m & 127) << 6);
  int n0 = tid, n1 = tid + 256;
  W[base + ((long)(n0 >> 6) << 13) + ((n0 & 63) ^ ((m & 7) << 3))] = (_Float16)(e0 * inv);
  W[base + ((long)(n1 >> 6) << 13) + ((n1 & 63) ^ ((m & 7) << 3))] = (_Float16)(e1 * inv);
}

// ---- 32x32 tiled transpose, fp32 -> fp32 row-major ------------------------
__global__ __launch_bounds__(256) void transpose_f32(
    const float* __restrict__ src, float* __restrict__ dst, int R, int Ccols)
{
  __shared__ float t[32][33];
  const long bo = (long)blockIdx.z * R * Ccols;
  const int c0 = blockIdx.x * 32, r0 = blockIdx.y * 32;
  const int tx = threadIdx.x, ty = threadIdx.y;
#pragma unroll
  for (int j = 0; j < 4; ++j)
    t[ty + j * 8][tx] = src[bo + (long)(r0 + ty + j * 8) * Ccols + c0 + tx];
  __syncthreads();
#pragma unroll
  for (int j = 0; j < 4; ++j)
    dst[bo + (long)(c0 + ty + j * 8) * R + r0 + tx] = t[tx][ty + j * 8];
}

// ---- 32x32 tiled transpose, fp32 -> fp16 tiled-swizzled (kdim = R) --------
__global__ __launch_bounds__(256) void transpose_f16_swz(
    const float* __restrict__ src, _Float16* __restrict__ dst, int R, int Ccols)
{
  __shared__ float t[32][33];
  const long bi = (long)blockIdx.z * R * Ccols;
  const int c0 = blockIdx.x * 32, r0 = blockIdx.y * 32;
  const int tx = threadIdx.x, ty = threadIdx.y;
  const int ktiles = R >> 6;
#pragma unroll
  for (int j = 0; j < 4; ++j)
    t[ty + j * 8][tx] = src[bi + (long)(r0 + ty + j * 8) * Ccols + c0 + tx];
  __syncthreads();
#pragma unroll
  for (int j = 0; j < 4; ++j) {
    int orow = c0 + ty + j * 8, ocol = r0 + tx;
    long idx = bi + ((long)((orow >> 7) * ktiles + (ocol >> 6)) << 13)
             + ((orow & 127) << 6) + ((ocol & 63) ^ ((orow & 7) << 3));
    dst[idx] = (_Float16)t[tx][ty + j * 8];
  }
}

extern "C" void kernel_launch(void* const* d_in, const int* in_sizes, int n_in,
                              void* d_out, int out_size, void* d_ws, size_t ws_size,
                              hipStream_t stream) {
  const float* q = (const float*)d_in[0];
  const float* p = (const float*)d_in[1];
  const int* q_mask = (const int*)d_in[2];
  const int* p_mask = (const int*)d_in[3];
  const float* W1 = (const float*)d_in[4];
  const float* W2 = (const float*)d_in[5];
  float* out_p = (float*)d_out;
  float* out_q = out_p + (size_t)B_DIM * M_SEQ * V_DIM;

  char* ws = (char*)d_ws;
  const size_t MB = 1048576;
  _Float16* W1h = (_Float16*)(ws + 0 * MB);
  _Float16* W2h = (_Float16*)(ws + 2 * MB);
  _Float16* xh  = (_Float16*)(ws + 4 * MB);
  _Float16* xl  = (_Float16*)(ws + 20 * MB);
  _Float16* sqh = (_Float16*)(ws + 36 * MB);
  _Float16* sql = (_Float16*)(ws + 52 * MB);
  _Float16* sph = (_Float16*)(ws + 68 * MB);
  float*    s   = (float*)(ws + 4 * MB);     // over xh/xl (dead after projections)
  float*    st  = (float*)(ws + 20 * MB);
  _Float16* wq  = (_Float16*)(ws + 68 * MB); // over sph (dead after scores)
  _Float16* wp  = (_Float16*)(ws + 84 * MB);
  _Float16* pT  = (_Float16*)(ws + 36 * MB); // over sqh (dead after scores)
  _Float16* qT  = (_Float16*)(ws + 52 * MB); // over sql

  dim3 blk(256);

  // 1) split weights (hi only) and q (hi+lo) into swizzled tiles
  split_f16_swz<<<512, blk, 0, stream>>>(W1, W1h, nullptr);
  split_f16_swz<<<512, blk, 0, stream>>>(W2, W2h, nullptr);
  split_f16_swz<<<4096, blk, 0, stream>>>(q, xh, xl);

  // 2) proj_q: s_q = relu(q @ W1^T), fp16 split output (hi+lo)
  gemm_swz<2, true, 2><<<dim3(8, 64, 1), blk, 0, stream>>>(
      xh, xl, W1h, nullptr, sqh, sql, 16, 0, 0, 0, 0, 16);

  // 3) split p, proj_p: s_p = relu(p @ W2^T), fp16 hi only
  split_f16_swz<<<4096, blk, 0, stream>>>(p, xh, xl);
  gemm_swz<2, true, 1><<<dim3(8, 64, 1), blk, 0, stream>>>(
      xh, xl, W2h, nullptr, sph, nullptr, 16, 0, 0, 0, 0, 16);

  // 4) scores: s[b] = s_q[b] @ s_p[b]^T, fp32 out
  gemm_swz<2, false, 0><<<dim3(4, 4, 16), blk, 0, stream>>>(
      sqh, sql, sph, s, nullptr, nullptr, 16, 512, 64, 64, 262144L, 0);

  // 5) s^T, softmaxes
  transpose_f32<<<dim3(16, 16, 16), dim3(32, 8), 0, stream>>>(s, st, 512, 512);
  softmax_swz<<<8192, blk, 0, stream>>>(s, p_mask, wp);
  softmax_swz<<<8192, blk, 0, stream>>>(st, q_mask, wq);

  // 6) p^T, q^T as swizzled fp16 (kdim = 512)
  transpose_f16_swz<<<dim3(32, 16, 16), dim3(32, 8), 0, stream>>>(p, pT, 512, 1024);
  transpose_f16_swz<<<dim3(32, 16, 16), dim3(32, 8), 0, stream>>>(q, qT, 512, 1024);

  // 7) out_q[b] = wp[b] @ pT[b]^T ; out_p[b] = wq[b] @ qT[b]^T
  gemm_swz<1, false, 0><<<dim3(8, 4, 16), blk, 0, stream>>>(
      wp, nullptr, pT, out_q, nullptr, nullptr, 8, 1024, 32, 64, 524288L, 0);
  gemm_swz<1, false, 0><<<dim3(8, 4, 16), blk, 0, stream>>>(
      wq, nullptr, qT, out_p, nullptr, nullptr, 8, 1024, 32, 64, 524288L, 0);
}

// Round 4
// 188.590 us; speedup vs baseline: 1.5536x; 1.2262x over previous
//
#include <hip/hip_runtime.h>

// BiAttention: B=16, M=N=512, V=A=1024, all-fp16 MFMA pipeline.
//   s_q = relu(q @ W1^T), s_p = relu(p @ W2^T)   [fp16 1-term GEMM, fp32 acc]
//   s   = s_q @ s_p^T (batched)                  [fp16 2-term split A, 1-term B]
//   wp  = softmax_n(s), wq = softmax_m(s^T)
//   out_q = wp @ p, out_p = wq @ q               [fp16 1-term GEMM]
//
// s_q is split hi+lo in the projection epilogue (fp32 accumulator there), so
// the score GEMM A-side is ~exact; remaining error = fp16 rounding of inputs
// and of s_p (~7e-4 rel) -> delta(s)_rms ~ 7e-3, absmax ~0.05 < 0.108.
//
// fp16 GEMM operands live in a TILED+SWIZZLED global layout:
//   tiles of 128x64, elem (r,k) at tile[(r&127)*64 + ((k&63) ^ ((r&7)<<3))]
// staged linearly with global_load_lds(16B); ds_read_b128 conflict-free.
//
// GEMM K-loop: single-barrier 2-phase (guide T3-minimum):
//   stage(t+1) -> ds_read(cur) -> setprio(1) MFMA setprio(0) -> vmcnt(0) -> barrier
//
// Workspace (92 MiB):
//   [0,2) W1h  [2,4) W2h
//   [4,20) qh   [20,36) ph          (contiguous A for merged projection)
//   [36,52) sqh [52,68) sph [68,84) sql   (proj C, z-stride 16MB: z0->sqh, z1->sph)
//   after projections:  s fp32 [4,20) (over qh), st fp32 [20,36) (over ph)
//   after scores:       wp [36,44) wq [44,52) (over sqh)
//                       pT [52,68) (over sph)  qT [68,84) (over sql)

#define B_DIM 16
#define M_SEQ 512
#define V_DIM 1024

typedef _Float16 f16x8 __attribute__((ext_vector_type(8)));
typedef float f32x4 __attribute__((ext_vector_type(4)));

__device__ __forceinline__ long swzi(int r, int k, int ktiles) {
  return ((long)((r >> 7) * ktiles + (k >> 6)) << 13)
       + ((r & 127) << 6) + ((k & 63) ^ ((r & 7) << 3));
}

// ---- fp32 -> fp16 (hi only) into tiled-swizzled layout, row length 1024 ---
__global__ __launch_bounds__(256) void split_f16_swz(
    const float* __restrict__ src, _Float16* __restrict__ h)
{
  long g = (long)blockIdx.x * 256 + threadIdx.x;   // one thread per 8 elems
  int r = (int)(g >> 7);
  int c8 = ((int)g & 127) << 3;
  const float4* s4 = reinterpret_cast<const float4*>(src + ((long)r << 10) + c8);
  float4 f0 = s4[0], f1 = s4[1];
  f16x8 hh;
  hh[0] = (_Float16)f0.x; hh[1] = (_Float16)f0.y;
  hh[2] = (_Float16)f0.z; hh[3] = (_Float16)f0.w;
  hh[4] = (_Float16)f1.x; hh[5] = (_Float16)f1.y;
  hh[6] = (_Float16)f1.z; hh[7] = (_Float16)f1.w;
  *(f16x8*)(h + swzi(r, c8, 16)) = hh;
}

// ---- unified NT GEMM on swizzled fp16 tiles -------------------------------
// NTERMS=2: A = [Ah | Al] along K (K_eff = 2*ktr tiles).
// OUTMODE: 0 = fp32 row-major; 2 = fp16 swizzled hi (+ lo for bz < loZMax).
template<int NTERMS, bool RELU, int OUTMODE>
__global__ __launch_bounds__(256, 2) void gemm_swz(
    const _Float16* __restrict__ Ah, const _Float16* __restrict__ Al,
    const _Float16* __restrict__ Bh, const _Float16* __restrict__ Bh2,
    float* __restrict__ Cf, _Float16* __restrict__ Ch, _Float16* __restrict__ Cl,
    const int loZMax, const int ktr, const int ldc,
    const long aBatchTiles, const long bBatchTiles, const long cBatchElems,
    const int cTilesRow, const long cOff0, const long cOff1, const int cSplit)
{
  __shared__ _Float16 sA[2][8192], sB[2][8192];

  // XCD-chunked block swizzle (all grids have nwg % 8 == 0)
  const int gx = gridDim.x, gy = gridDim.y;
  long nwg = (long)gx * gy * gridDim.z;
  long bid = blockIdx.x + (long)gx * (blockIdx.y + (long)gy * blockIdx.z);
  long chunk = nwg >> 3;
  long o = (bid & 7) * chunk + (bid >> 3);
  const int bx = (int)(o % gx);
  const int by = (int)((o / gx) % gy);
  const int bz = (int)(o / ((long)gx * gy));

  const int tid = threadIdx.x;
  const int lane = tid & 63, wave = tid >> 6;
  const int wr = wave >> 1, wc = wave & 1;
  const int lrow = lane & 15;
  const int kb = (lane >> 4) << 4;        // byte offset of 8-elem group in 32-k window
  const int sw = (lrow & 7) << 4;         // byte XOR swizzle for this lane's rows

  const _Float16* Bsel = (Bh2 != nullptr && bz != 0) ? Bh2 : Bh;
  const long aRow = (long)bz * aBatchTiles + (long)by * ktr;
  const long bRow = (long)bz * bBatchTiles + (long)bx * ktr;
  const int NT = NTERMS * ktr;

  f32x4 acc[4][4] = {};

  auto stage = [&](int buf, int t) {
    int kt = t;
    const _Float16* As = Ah;
    if (NTERMS == 2 && t >= ktr) { As = Al; kt = t - ktr; }
    const _Float16* ga = As + ((aRow + kt) << 13) + tid * 8;
    const _Float16* gb = Bsel + ((bRow + kt) << 13) + tid * 8;
    _Float16* la = &sA[buf][(tid & 192) * 8];
    _Float16* lb = &sB[buf][(tid & 192) * 8];
#pragma unroll
    for (int j = 0; j < 4; ++j) {
      __builtin_amdgcn_global_load_lds(
          (const __attribute__((address_space(1))) void*)(ga + j * 2048),
          (__attribute__((address_space(3))) void*)(la + j * 2048), 16, 0, 0);
      __builtin_amdgcn_global_load_lds(
          (const __attribute__((address_space(1))) void*)(gb + j * 2048),
          (__attribute__((address_space(3))) void*)(lb + j * 2048), 16, 0, 0);
    }
  };

  auto compute = [&](int buf) {
    const char* baseA = (const char*)&sA[buf][0] + (wr * 64 + lrow) * 128;
    const char* baseB = (const char*)&sB[buf][0] + (wc * 64 + lrow) * 128;
    f16x8 a[2][4], b[2][4];
#pragma unroll
    for (int ks = 0; ks < 2; ++ks) {
      const int cb = (ks * 64 + kb) ^ sw;
#pragma unroll
      for (int i = 0; i < 4; ++i) {
        a[ks][i] = *(const f16x8*)(baseA + i * 2048 + cb);
        b[ks][i] = *(const f16x8*)(baseB + i * 2048 + cb);
      }
    }
    __builtin_amdgcn_s_setprio(1);
#pragma unroll
    for (int ks = 0; ks < 2; ++ks)
#pragma unroll
      for (int mi = 0; mi < 4; ++mi)
#pragma unroll
        for (int ni = 0; ni < 4; ++ni)
          acc[mi][ni] = __builtin_amdgcn_mfma_f32_16x16x32_f16(a[ks][mi], b[ks][ni], acc[mi][ni], 0, 0, 0);
    __builtin_amdgcn_s_setprio(0);
  };

  // prologue
  stage(0, 0);
  asm volatile("s_waitcnt vmcnt(0)" ::: "memory");
  __syncthreads();

  int cur = 0;
  for (int t = 0; t < NT; ++t) {
    if (t + 1 < NT) stage(cur ^ 1, t + 1);   // next-tile loads fly under compute
    compute(cur);
    if (t + 1 < NT) asm volatile("s_waitcnt vmcnt(0)" ::: "memory");
    __syncthreads();                          // single barrier per tile
    cur ^= 1;
  }

  const int r0 = by * 128 + wr * 64 + ((lane >> 4) << 2);
  const int c0 = bx * 128 + wc * 64 + (lane & 15);
  if (OUTMODE == 0) {
    long cbase = cSplit ? (bz < 16 ? cOff0 + (long)bz * cBatchElems
                                   : cOff1 + (long)(bz - 16) * cBatchElems)
                        : (long)bz * cBatchElems;
    float* Cb = Cf + cbase;
#pragma unroll
    for (int mi = 0; mi < 4; ++mi)
#pragma unroll
      for (int ni = 0; ni < 4; ++ni)
#pragma unroll
        for (int r2 = 0; r2 < 4; ++r2)
          Cb[(long)(r0 + mi * 16 + r2) * ldc + c0 + ni * 16] = acc[mi][ni][r2];
  } else {
    const bool wlo = (bz < loZMax);
#pragma unroll
    for (int mi = 0; mi < 4; ++mi)
#pragma unroll
      for (int ni = 0; ni < 4; ++ni)
#pragma unroll
        for (int r2 = 0; r2 < 4; ++r2) {
          int r = r0 + mi * 16 + r2, c = c0 + ni * 16;
          float x = acc[mi][ni][r2];
          if (RELU) x = fmaxf(x, 0.0f);
          long idx = (long)bz * cBatchElems
                   + ((long)((r >> 7) * cTilesRow + (c >> 6)) << 13)
                   + ((r & 127) << 6) + ((c & 63) ^ ((r & 7) << 3));
          _Float16 hv = (_Float16)x;
          Ch[idx] = hv;
          if (wlo) Cl[idx] = (_Float16)(x - (float)hv);
        }
  }
}

// ---- row softmax (512 cols), fp16 swizzled weights out (kdim=512) --------
__global__ __launch_bounds__(256) void softmax_swz(
    const float* __restrict__ S, const int* __restrict__ mask, _Float16* __restrict__ W)
{
  const int row = blockIdx.x;              // b*512 + m
  const int b = row >> 9, m = row & 511;
  const float* Sr = S + (long)row * 512;
  const int* mr = mask + (long)b * 512;
  const int tid = threadIdx.x;
  const int lane = tid & 63, wave = tid >> 6;
  __shared__ float red[4];

  float v0 = mr[tid] ? Sr[tid] : -1e30f;
  float v1 = mr[tid + 256] ? Sr[tid + 256] : -1e30f;
  float mx = fmaxf(v0, v1);
#pragma unroll
  for (int of = 32; of >= 1; of >>= 1) mx = fmaxf(mx, __shfl_xor(mx, of, 64));
  if (lane == 0) red[wave] = mx;
  __syncthreads();
  mx = fmaxf(fmaxf(red[0], red[1]), fmaxf(red[2], red[3]));
  __syncthreads();
  float e0 = __expf(v0 - mx), e1 = __expf(v1 - mx);
  float sm = e0 + e1;
#pragma unroll
  for (int of = 32; of >= 1; of >>= 1) sm += __shfl_xor(sm, of, 64);
  if (lane == 0) red[wave] = sm;
  __syncthreads();
  float inv = 1.0f / (red[0] + red[1] + red[2] + red[3]);

  long base = (long)b * 262144 + ((long)((m >> 7) * 8) << 13) + ((m & 127) << 6);
  int n0 = tid, n1 = tid + 256;
  W[base + ((long)(n0 >> 6) << 13) + ((n0 & 63) ^ ((m & 7) << 3))] = (_Float16)(e0 * inv);
  W[base + ((long)(n1 >> 6) << 13) + ((n1 & 63) ^ ((m & 7) << 3))] = (_Float16)(e1 * inv);
}

// ---- 32x32 tiled transpose, fp32 -> fp32 row-major ------------------------
__global__ __launch_bounds__(256) void transpose_f32(
    const float* __restrict__ src, float* __restrict__ dst, int R, int Ccols)
{
  __shared__ float t[32][33];
  const long bo = (long)blockIdx.z * R * Ccols;
  const int c0 = blockIdx.x * 32, r0 = blockIdx.y * 32;
  const int tx = threadIdx.x, ty = threadIdx.y;
#pragma unroll
  for (int j = 0; j < 4; ++j)
    t[ty + j * 8][tx] = src[bo + (long)(r0 + ty + j * 8) * Ccols + c0 + tx];
  __syncthreads();
#pragma unroll
  for (int j = 0; j < 4; ++j)
    dst[bo + (long)(c0 + ty + j * 8) * R + r0 + tx] = t[tx][ty + j * 8];
}

// ---- 32x32 tiled transpose, fp32 -> fp16 tiled-swizzled (kdim = R) --------
__global__ __launch_bounds__(256) void transpose_f16_swz(
    const float* __restrict__ src, _Float16* __restrict__ dst, int R, int Ccols)
{
  __shared__ float t[32][33];
  const long bi = (long)blockIdx.z * R * Ccols;
  const int c0 = blockIdx.x * 32, r0 = blockIdx.y * 32;
  const int tx = threadIdx.x, ty = threadIdx.y;
  const int ktiles = R >> 6;
#pragma unroll
  for (int j = 0; j < 4; ++j)
    t[ty + j * 8][tx] = src[bi + (long)(r0 + ty + j * 8) * Ccols + c0 + tx];
  __syncthreads();
#pragma unroll
  for (int j = 0; j < 4; ++j) {
    int orow = c0 + ty + j * 8, ocol = r0 + tx;
    long idx = bi + ((long)((orow >> 7) * ktiles + (ocol >> 6)) << 13)
             + ((orow & 127) << 6) + ((ocol & 63) ^ ((orow & 7) << 3));
    dst[idx] = (_Float16)t[tx][ty + j * 8];
  }
}

extern "C" void kernel_launch(void* const* d_in, const int* in_sizes, int n_in,
                              void* d_out, int out_size, void* d_ws, size_t ws_size,
                              hipStream_t stream) {
  const float* q = (const float*)d_in[0];
  const float* p = (const float*)d_in[1];
  const int* q_mask = (const int*)d_in[2];
  const int* p_mask = (const int*)d_in[3];
  const float* W1 = (const float*)d_in[4];
  const float* W2 = (const float*)d_in[5];
  float* out = (float*)d_out;   // [out_p | out_q], handled via cSplit offsets

  char* ws = (char*)d_ws;
  const size_t MB = 1048576;
  _Float16* W1h = (_Float16*)(ws + 0 * MB);
  _Float16* W2h = (_Float16*)(ws + 2 * MB);
  _Float16* qh  = (_Float16*)(ws + 4 * MB);   // + ph at +16MB (contiguous A)
  _Float16* ph  = (_Float16*)(ws + 20 * MB);
  _Float16* sqh = (_Float16*)(ws + 36 * MB);  // + sph at +16MB (contiguous C)
  _Float16* sph = (_Float16*)(ws + 52 * MB);
  _Float16* sql = (_Float16*)(ws + 68 * MB);
  float*    s   = (float*)(ws + 4 * MB);      // over qh (dead after projections)
  float*    st  = (float*)(ws + 20 * MB);     // over ph
  _Float16* wp  = (_Float16*)(ws + 36 * MB);  // over sqh (dead after scores)
  _Float16* wq  = (_Float16*)(ws + 44 * MB);
  _Float16* pT  = (_Float16*)(ws + 52 * MB);  // over sph
  _Float16* qT  = (_Float16*)(ws + 68 * MB);  // over sql

  dim3 blk(256);

  // 1) fp16-hi conversions into swizzled tiles
  split_f16_swz<<<512, blk, 0, stream>>>(W1, W1h);
  split_f16_swz<<<512, blk, 0, stream>>>(W2, W2h);
  split_f16_swz<<<4096, blk, 0, stream>>>(q, qh);
  split_f16_swz<<<4096, blk, 0, stream>>>(p, ph);

  // 2) merged projections (z=0: q@W1 -> sqh+sql, z=1: p@W2 -> sph)
  gemm_swz<1, true, 2><<<dim3(8, 64, 2), blk, 0, stream>>>(
      qh, nullptr, W1h, W2h, nullptr, sqh, sql,
      /*loZMax=*/1, /*ktr=*/16, /*ldc=*/0,
      /*aBatchTiles=*/1024, /*bBatchTiles=*/0, /*cBatchElems=*/8388608L,
      /*cTilesRow=*/16, 0, 0, 0);

  // 3) scores: s[b] = s_q[b] @ s_p[b]^T  (A = hi+lo, B = hi), fp32 out
  gemm_swz<2, false, 0><<<dim3(4, 4, 16), blk, 0, stream>>>(
      sqh, sql, sph, nullptr, s, nullptr, nullptr,
      0, 16, 512, 64, 64, 262144L, 0, 0, 0, 0);

  // 4) s^T, softmaxes
  transpose_f32<<<dim3(16, 16, 16), dim3(32, 8), 0, stream>>>(s, st, 512, 512);
  softmax_swz<<<8192, blk, 0, stream>>>(s, p_mask, wp);
  softmax_swz<<<8192, blk, 0, stream>>>(st, q_mask, wq);

  // 5) p^T, q^T as swizzled fp16 (kdim = 512)
  transpose_f16_swz<<<dim3(32, 16, 16), dim3(32, 8), 0, stream>>>(p, pT, 512, 1024);
  transpose_f16_swz<<<dim3(32, 16, 16), dim3(32, 8), 0, stream>>>(q, qT, 512, 1024);

  // 6) merged output GEMMs: z<16: out_q = wp@pT^T; z>=16: out_p = wq@qT^T
  gemm_swz<1, false, 0><<<dim3(8, 4, 32), blk, 0, stream>>>(
      wp, nullptr, pT, nullptr, out, nullptr, nullptr,
      0, 8, 1024, 32, 64, 524288L, 0,
      /*cOff0=*/8388608L, /*cOff1=*/0L, /*cSplit=*/1);
}

// Round 5
// 182.170 us; speedup vs baseline: 1.6084x; 1.0352x over previous
//
#include <hip/hip_runtime.h>

// BiAttention: B=16, M=N=512, V=A=1024, all-fp16 MFMA pipeline.
//   s_q = relu(q @ W1^T), s_p = relu(p @ W2^T)   [fp16 GEMM, 256^2 8-phase]
//   s   = s_q @ s_p^T (batched)                  [fp16 2-term split A, 128^2]
//   wp  = softmax_n(s), wq = softmax_m(s^T)
//   out_q = wp @ p, out_p = wq @ q               [fp16 GEMM, 256^2 8-phase]
//
// s_q is split hi+lo in the projection epilogue (fp32 accumulator), so the
// score GEMM A-side is ~exact; error ~= fp16 rounding of inputs/s_p only.
//
// fp16 GEMM operands live in a TILED+SWIZZLED global layout:
//   tiles of 128x64, elem (r,k) at tile[(r&127)*64 + ((k&63) ^ ((r&7)<<3))]
// staged linearly with global_load_lds(16B); ds_read_b128 conflict-free (T2).
//
// gemm256: 256x256 tile, BK=64, 512 thr / 8 waves (2Mx4N), 128KiB dbuf LDS,
// 4 phases/K-tile {ds_read || stage -> s_barrier -> lgkmcnt(0) -> 16 MFMA ->
// s_barrier}, counted drain only at iteration end (T3+T4), setprio (T5),
// XCD-chunked block swizzle (T1).
//
// Workspace (92 MiB):
//   [0,2) W1h  [2,4) W2h
//   [4,20) qh   [20,36) ph
//   [36,52) sqh [52,68) sph [68,84) sql
//   after projections:  s fp32 [4,20), st fp32 [20,36)
//   after scores:       wp [36,44) wq [44,52), pT [52,68), qT [68,84)

#define B_DIM 16
#define M_SEQ 512
#define V_DIM 1024

typedef _Float16 f16x8 __attribute__((ext_vector_type(8)));
typedef float f32x4 __attribute__((ext_vector_type(4)));

__device__ __forceinline__ long swzi(int r, int k, int ktiles) {
  return ((long)((r >> 7) * ktiles + (k >> 6)) << 13)
       + ((r & 127) << 6) + ((k & 63) ^ ((r & 7) << 3));
}

// ---- fp32 -> fp16 (hi only) into tiled-swizzled layout, row length 1024 ---
__global__ __launch_bounds__(256) void split_f16_swz(
    const float* __restrict__ src, _Float16* __restrict__ h)
{
  long g = (long)blockIdx.x * 256 + threadIdx.x;   // one thread per 8 elems
  int r = (int)(g >> 7);
  int c8 = ((int)g & 127) << 3;
  const float4* s4 = reinterpret_cast<const float4*>(src + ((long)r << 10) + c8);
  float4 f0 = s4[0], f1 = s4[1];
  f16x8 hh;
  hh[0] = (_Float16)f0.x; hh[1] = (_Float16)f0.y;
  hh[2] = (_Float16)f0.z; hh[3] = (_Float16)f0.w;
  hh[4] = (_Float16)f1.x; hh[5] = (_Float16)f1.y;
  hh[6] = (_Float16)f1.z; hh[7] = (_Float16)f1.w;
  *(f16x8*)(h + swzi(r, c8, 16)) = hh;
}

// ---- 256^2 8-phase NT GEMM on swizzled fp16 tiles (1-term) ---------------
// OUTMODE 0: fp32 row-major (cSplit batch offsets). OUTMODE 2: fp16 swizzled
// hi (+ lo for bz < loZMax).
template<bool RELU, int OUTMODE>
__global__ __launch_bounds__(512, 2) void gemm256(
    const _Float16* __restrict__ A,
    const _Float16* __restrict__ Bh, const _Float16* __restrict__ Bh2,
    float* __restrict__ Cf, _Float16* __restrict__ Ch, _Float16* __restrict__ Cl,
    const int loZMax, const int ktr, const int ldc,
    const long aBatchTiles, const long bBatchTiles, const long cBatchElems,
    const int cTilesRow, const long cOff0, const long cOff1, const int cSplit)
{
  __shared__ _Float16 sA[2][16384];   // 2 x (two 128x64 tiles)
  __shared__ _Float16 sB[2][16384];

  // XCD-chunked block swizzle (nwg % 8 == 0)
  const int gx = gridDim.x, gy = gridDim.y;
  long nwg = (long)gx * gy * gridDim.z;
  long bid = blockIdx.x + (long)gx * (blockIdx.y + (long)gy * blockIdx.z);
  long chunk = nwg >> 3;
  long o = (bid & 7) * chunk + (bid >> 3);
  const int bx = (int)(o % gx);
  const int by = (int)((o / gx) % gy);
  const int bz = (int)(o / ((long)gx * gy));

  const int tid = threadIdx.x;
  const int lane = tid & 63, w = tid >> 6;
  const int wm = w >> 2, wn = w & 3;          // 2 x 4 wave grid
  const int lrow = lane & 15;
  const int kb = (lane >> 4) << 4;            // byte offset of 8-elem k-group
  const int sw = (lrow & 7) << 4;             // XOR byte swizzle

  const _Float16* Bsel = (Bh2 != nullptr && bz != 0) ? Bh2 : Bh;
  const long aT0 = (long)bz * aBatchTiles + (long)(by * 2) * ktr;
  const long aT1 = aT0 + ktr;
  const long bT0 = (long)bz * bBatchTiles + (long)(bx * 2) * ktr;
  const long bT1 = bT0 + ktr;

  f32x4 acc[8][4] = {};

  // stage: 4 loads for A (2 tiles) or B; LDS dest wave-uniform, 16B/lane
  auto stageA = [&](int buf, int kt) {
#pragma unroll
    for (int j = 0; j < 4; ++j) {
      const _Float16* g = A + (((j < 2 ? aT0 : aT1) + kt) << 13)
                            + ((j & 1) * 4096 + w * 512 + lane * 8);
      __builtin_amdgcn_global_load_lds(
          (const __attribute__((address_space(1))) void*)g,
          (__attribute__((address_space(3))) void*)(&sA[buf][j * 4096 + w * 512]),
          16, 0, 0);
    }
  };
  auto stageB = [&](int buf, int kt) {
#pragma unroll
    for (int j = 0; j < 4; ++j) {
      const _Float16* g = Bsel + (((j < 2 ? bT0 : bT1) + kt) << 13)
                               + ((j & 1) * 4096 + w * 512 + lane * 8);
      __builtin_amdgcn_global_load_lds(
          (const __attribute__((address_space(1))) void*)g,
          (__attribute__((address_space(3))) void*)(&sB[buf][j * 4096 + w * 512]),
          16, 0, 0);
    }
  };

  // prologue: tile 0 into buf 0
  stageA(0, 0);
  stageB(0, 0);
  asm volatile("s_waitcnt vmcnt(0)" ::: "memory");
  __builtin_amdgcn_s_barrier();

  const char* baseA0 = (const char*)&sA[0][0] + wm * 16384 + lrow * 128;
  const char* baseB0 = (const char*)&sB[0][0] + (wn >> 1) * 16384
                     + ((wn & 1) * 64 + lrow) * 128;

  for (int t = 0; t < ktr; ++t) {
    const int cur = t & 1, nxt = cur ^ 1;
    const char* cA = baseA0 + cur * 32768;
    const char* cB = baseB0 + cur * 32768;
#pragma unroll
    for (int p = 0; p < 4; ++p) {
      const int mh = p & 1, ks = p >> 1;
      const int co = (ks * 64 + kb) ^ sw;
      f16x8 a[4], b[4];
#pragma unroll
      for (int i = 0; i < 4; ++i) {
        a[i] = *(const f16x8*)(cA + (mh * 64 + i * 16) * 128 + co);
        b[i] = *(const f16x8*)(cB + (i * 16) * 128 + co);
      }
      if (t + 1 < ktr) {
        if (p == 0) stageA(nxt, t + 1);
        else if (p == 1) stageB(nxt, t + 1);
      }
      __builtin_amdgcn_s_barrier();
      asm volatile("s_waitcnt lgkmcnt(0)" ::: "memory");
      __builtin_amdgcn_sched_barrier(0);
      __builtin_amdgcn_s_setprio(1);
#pragma unroll
      for (int mi = 0; mi < 4; ++mi)
#pragma unroll
        for (int ni = 0; ni < 4; ++ni)
          acc[mh * 4 + mi][ni] = __builtin_amdgcn_mfma_f32_16x16x32_f16(
              a[mi], b[ni], acc[mh * 4 + mi][ni], 0, 0, 0);
      __builtin_amdgcn_s_setprio(0);
      if (p == 3 && t + 1 < ktr)
        asm volatile("s_waitcnt vmcnt(0)" ::: "memory");
      __builtin_amdgcn_s_barrier();
    }
  }

  const int rb = by * 256 + wm * 128 + ((lane >> 4) << 2);
  const int cb = bx * 256 + wn * 64 + (lane & 15);
  if (OUTMODE == 0) {
    long cbase = cSplit ? (bz < 16 ? cOff0 + (long)bz * cBatchElems
                                   : cOff1 + (long)(bz - 16) * cBatchElems)
                        : (long)bz * cBatchElems;
    float* Cb = Cf + cbase;
#pragma unroll
    for (int mi = 0; mi < 8; ++mi)
#pragma unroll
      for (int ni = 0; ni < 4; ++ni)
#pragma unroll
        for (int r2 = 0; r2 < 4; ++r2)
          Cb[(long)(rb + mi * 16 + r2) * ldc + cb + ni * 16] = acc[mi][ni][r2];
  } else {
    const bool wlo = (bz < loZMax);
#pragma unroll
    for (int mi = 0; mi < 8; ++mi)
#pragma unroll
      for (int ni = 0; ni < 4; ++ni)
#pragma unroll
        for (int r2 = 0; r2 < 4; ++r2) {
          int r = rb + mi * 16 + r2, c = cb + ni * 16;
          float x = acc[mi][ni][r2];
          if (RELU) x = fmaxf(x, 0.0f);
          long idx = (long)bz * cBatchElems
                   + ((long)((r >> 7) * cTilesRow + (c >> 6)) << 13)
                   + ((r & 127) << 6) + ((c & 63) ^ ((r & 7) << 3));
          _Float16 hv = (_Float16)x;
          Ch[idx] = hv;
          if (wlo) Cl[idx] = (_Float16)(x - (float)hv);
        }
  }
}

// ---- 128^2 NT GEMM on swizzled fp16 tiles, 2-term A (scores) -------------
template<int NTERMS, bool RELU>
__global__ __launch_bounds__(256, 2) void gemm_swz(
    const _Float16* __restrict__ Ah, const _Float16* __restrict__ Al,
    const _Float16* __restrict__ Bh,
    float* __restrict__ Cf,
    const int ktr, const int ldc,
    const long aBatchTiles, const long bBatchTiles, const long cBatchElems)
{
  __shared__ _Float16 sA[2][8192], sB[2][8192];

  const int gx = gridDim.x, gy = gridDim.y;
  long nwg = (long)gx * gy * gridDim.z;
  long bid = blockIdx.x + (long)gx * (blockIdx.y + (long)gy * blockIdx.z);
  long chunk = nwg >> 3;
  long o = (bid & 7) * chunk + (bid >> 3);
  const int bx = (int)(o % gx);
  const int by = (int)((o / gx) % gy);
  const int bz = (int)(o / ((long)gx * gy));

  const int tid = threadIdx.x;
  const int lane = tid & 63, wave = tid >> 6;
  const int wr = wave >> 1, wc = wave & 1;
  const int lrow = lane & 15;
  const int kb = (lane >> 4) << 4;
  const int sw = (lrow & 7) << 4;

  const long aRow = (long)bz * aBatchTiles + (long)by * ktr;
  const long bRow = (long)bz * bBatchTiles + (long)bx * ktr;
  const int NT = NTERMS * ktr;

  f32x4 acc[4][4] = {};

  auto stage = [&](int buf, int t) {
    int kt = t;
    const _Float16* As = Ah;
    if (NTERMS == 2 && t >= ktr) { As = Al; kt = t - ktr; }
    const _Float16* ga = As + ((aRow + kt) << 13) + tid * 8;
    const _Float16* gb = Bh + ((bRow + kt) << 13) + tid * 8;
    _Float16* la = &sA[buf][(tid & 192) * 8];
    _Float16* lb = &sB[buf][(tid & 192) * 8];
#pragma unroll
    for (int j = 0; j < 4; ++j) {
      __builtin_amdgcn_global_load_lds(
          (const __attribute__((address_space(1))) void*)(ga + j * 2048),
          (__attribute__((address_space(3))) void*)(la + j * 2048), 16, 0, 0);
      __builtin_amdgcn_global_load_lds(
          (const __attribute__((address_space(1))) void*)(gb + j * 2048),
          (__attribute__((address_space(3))) void*)(lb + j * 2048), 16, 0, 0);
    }
  };

  auto compute = [&](int buf) {
    const char* baseA = (const char*)&sA[buf][0] + (wr * 64 + lrow) * 128;
    const char* baseB = (const char*)&sB[buf][0] + (wc * 64 + lrow) * 128;
    f16x8 a[2][4], b[2][4];
#pragma unroll
    for (int ks = 0; ks < 2; ++ks) {
      const int cb2 = (ks * 64 + kb) ^ sw;
#pragma unroll
      for (int i = 0; i < 4; ++i) {
        a[ks][i] = *(const f16x8*)(baseA + i * 2048 + cb2);
        b[ks][i] = *(const f16x8*)(baseB + i * 2048 + cb2);
      }
    }
    __builtin_amdgcn_s_setprio(1);
#pragma unroll
    for (int ks = 0; ks < 2; ++ks)
#pragma unroll
      for (int mi = 0; mi < 4; ++mi)
#pragma unroll
        for (int ni = 0; ni < 4; ++ni)
          acc[mi][ni] = __builtin_amdgcn_mfma_f32_16x16x32_f16(a[ks][mi], b[ks][ni], acc[mi][ni], 0, 0, 0);
    __builtin_amdgcn_s_setprio(0);
  };

  stage(0, 0);
  asm volatile("s_waitcnt vmcnt(0)" ::: "memory");
  __syncthreads();

  int cur = 0;
  for (int t = 0; t < NT; ++t) {
    if (t + 1 < NT) stage(cur ^ 1, t + 1);
    compute(cur);
    if (t + 1 < NT) asm volatile("s_waitcnt vmcnt(0)" ::: "memory");
    __syncthreads();
    cur ^= 1;
  }

  const int r0 = by * 128 + wr * 64 + ((lane >> 4) << 2);
  const int c0 = bx * 128 + wc * 64 + (lane & 15);
  float* Cb = Cf + (long)bz * cBatchElems;
#pragma unroll
  for (int mi = 0; mi < 4; ++mi)
#pragma unroll
    for (int ni = 0; ni < 4; ++ni)
#pragma unroll
      for (int r2 = 0; r2 < 4; ++r2)
        Cb[(long)(r0 + mi * 16 + r2) * ldc + c0 + ni * 16] = acc[mi][ni][r2];
}

// ---- row softmax (512 cols), fp16 swizzled weights out (kdim=512) --------
__global__ __launch_bounds__(256) void softmax_swz(
    const float* __restrict__ S, const int* __restrict__ mask, _Float16* __restrict__ W)
{
  const int row = blockIdx.x;              // b*512 + m
  const int b = row >> 9, m = row & 511;
  const float* Sr = S + (long)row * 512;
  const int* mr = mask + (long)b * 512;
  const int tid = threadIdx.x;
  const int lane = tid & 63, wave = tid >> 6;
  __shared__ float red[4];

  float v0 = mr[tid] ? Sr[tid] : -1e30f;
  float v1 = mr[tid + 256] ? Sr[tid + 256] : -1e30f;
  float mx = fmaxf(v0, v1);
#pragma unroll
  for (int of = 32; of >= 1; of >>= 1) mx = fmaxf(mx, __shfl_xor(mx, of, 64));
  if (lane == 0) red[wave] = mx;
  __syncthreads();
  mx = fmaxf(fmaxf(red[0], red[1]), fmaxf(red[2], red[3]));
  __syncthreads();
  float e0 = __expf(v0 - mx), e1 = __expf(v1 - mx);
  float sm = e0 + e1;
#pragma unroll
  for (int of = 32; of >= 1; of >>= 1) sm += __shfl_xor(sm, of, 64);
  if (lane == 0) red[wave] = sm;
  __syncthreads();
  float inv = 1.0f / (red[0] + red[1] + red[2] + red[3]);

  long base = (long)b * 262144 + ((long)((m >> 7) * 8) << 13) + ((m & 127) << 6);
  int n0 = tid, n1 = tid + 256;
  W[base + ((long)(n0 >> 6) << 13) + ((n0 & 63) ^ ((m & 7) << 3))] = (_Float16)(e0 * inv);
  W[base + ((long)(n1 >> 6) << 13) + ((n1 & 63) ^ ((m & 7) << 3))] = (_Float16)(e1 * inv);
}

// ---- 32x32 tiled transpose, fp32 -> fp32 row-major ------------------------
__global__ __launch_bounds__(256) void transpose_f32(
    const float* __restrict__ src, float* __restrict__ dst, int R, int Ccols)
{
  __shared__ float t[32][33];
  const long bo = (long)blockIdx.z * R * Ccols;
  const int c0 = blockIdx.x * 32, r0 = blockIdx.y * 32;
  const int tx = threadIdx.x, ty = threadIdx.y;
#pragma unroll
  for (int j = 0; j < 4; ++j)
    t[ty + j * 8][tx] = src[bo + (long)(r0 + ty + j * 8) * Ccols + c0 + tx];
  __syncthreads();
#pragma unroll
  for (int j = 0; j < 4; ++j)
    dst[bo + (long)(c0 + ty + j * 8) * R + r0 + tx] = t[tx][ty + j * 8];
}

// ---- 32x32 tiled transpose, fp32 -> fp16 tiled-swizzled (kdim = R) --------
__global__ __launch_bounds__(256) void transpose_f16_swz(
    const float* __restrict__ src, _Float16* __restrict__ dst, int R, int Ccols)
{
  __shared__ float t[32][33];
  const long bi = (long)blockIdx.z * R * Ccols;
  const int c0 = blockIdx.x * 32, r0 = blockIdx.y * 32;
  const int tx = threadIdx.x, ty = threadIdx.y;
  const int ktiles = R >> 6;
#pragma unroll
  for (int j = 0; j < 4; ++j)
    t[ty + j * 8][tx] = src[bi + (long)(r0 + ty + j * 8) * Ccols + c0 + tx];
  __syncthreads();
#pragma unroll
  for (int j = 0; j < 4; ++j) {
    int orow = c0 + ty + j * 8, ocol = r0 + tx;
    long idx = bi + ((long)((orow >> 7) * ktiles + (ocol >> 6)) << 13)
             + ((orow & 127) << 6) + ((ocol & 63) ^ ((orow & 7) << 3));
    dst[idx] = (_Float16)t[tx][ty + j * 8];
  }
}

extern "C" void kernel_launch(void* const* d_in, const int* in_sizes, int n_in,
                              void* d_out, int out_size, void* d_ws, size_t ws_size,
                              hipStream_t stream) {
  const float* q = (const float*)d_in[0];
  const float* p = (const float*)d_in[1];
  const int* q_mask = (const int*)d_in[2];
  const int* p_mask = (const int*)d_in[3];
  const float* W1 = (const float*)d_in[4];
  const float* W2 = (const float*)d_in[5];
  float* out = (float*)d_out;   // [out_p | out_q]

  char* ws = (char*)d_ws;
  const size_t MB = 1048576;
  _Float16* W1h = (_Float16*)(ws + 0 * MB);
  _Float16* W2h = (_Float16*)(ws + 2 * MB);
  _Float16* qh  = (_Float16*)(ws + 4 * MB);   // ph at +16MB (contiguous A)
  _Float16* ph  = (_Float16*)(ws + 20 * MB);
  _Float16* sqh = (_Float16*)(ws + 36 * MB);  // sph at +16MB (contiguous C)
  _Float16* sph = (_Float16*)(ws + 52 * MB);
  _Float16* sql = (_Float16*)(ws + 68 * MB);
  float*    s   = (float*)(ws + 4 * MB);      // over qh (dead after projections)
  float*    st  = (float*)(ws + 20 * MB);     // over ph
  _Float16* wp  = (_Float16*)(ws + 36 * MB);  // over sqh; wq contiguous at +8MB
  _Float16* wq  = (_Float16*)(ws + 44 * MB);
  _Float16* pT  = (_Float16*)(ws + 52 * MB);  // over sph; qT contiguous at +16MB
  _Float16* qT  = (_Float16*)(ws + 68 * MB);  // over sql

  dim3 blk(256);

  // 1) fp16-hi conversions into swizzled tiles
  split_f16_swz<<<512, blk, 0, stream>>>(W1, W1h);
  split_f16_swz<<<512, blk, 0, stream>>>(W2, W2h);
  split_f16_swz<<<4096, blk, 0, stream>>>(q, qh);
  split_f16_swz<<<4096, blk, 0, stream>>>(p, ph);

  // 2) merged projections, 256^2 8-phase (z=0: q@W1 -> sqh+sql, z=1: p@W2 -> sph)
  gemm256<true, 2><<<dim3(4, 32, 2), dim3(512), 0, stream>>>(
      qh, W1h, W2h, nullptr, sqh, sql,
      /*loZMax=*/1, /*ktr=*/16, /*ldc=*/0,
      /*aBatchTiles=*/1024, /*bBatchTiles=*/0, /*cBatchElems=*/8388608L,
      /*cTilesRow=*/16, 0, 0, 0);

  // 3) scores: s[b] = s_q[b] @ s_p[b]^T  (A = hi|lo, B = hi), fp32 out
  gemm_swz<2, false><<<dim3(4, 4, 16), blk, 0, stream>>>(
      sqh, sql, sph, s, 16, 512, 64, 64, 262144L);

  // 4) s^T, softmaxes
  transpose_f32<<<dim3(16, 16, 16), dim3(32, 8), 0, stream>>>(s, st, 512, 512);
  softmax_swz<<<8192, blk, 0, stream>>>(s, p_mask, wp);
  softmax_swz<<<8192, blk, 0, stream>>>(st, q_mask, wq);

  // 5) p^T, q^T as swizzled fp16 (kdim = 512)
  transpose_f16_swz<<<dim3(32, 16, 16), dim3(32, 8), 0, stream>>>(p, pT, 512, 1024);
  transpose_f16_swz<<<dim3(32, 16, 16), dim3(32, 8), 0, stream>>>(q, qT, 512, 1024);

  // 6) merged output GEMMs, 256^2: z<16: out_q = wp@pT^T; z>=16: out_p = wq@qT^T
  gemm256<false, 0><<<dim3(4, 2, 32), dim3(512), 0, stream>>>(
      wp, pT, nullptr, out, nullptr, nullptr,
      0, /*ktr=*/8, /*ldc=*/1024,
      /*aBatchTiles=*/32, /*bBatchTiles=*/64, /*cBatchElems=*/524288L,
      0, /*cOff0=*/8388608L, /*cOff1=*/0L, /*cSplit=*/1);
}

// Round 6
// 175.857 us; speedup vs baseline: 1.6661x; 1.0359x over previous
//
#include <hip/hip_runtime.h>

// BiAttention: B=16, M=N=512, V=A=1024. fp16 MFMA pipeline, counted-vmcnt
// deep-pipelined GEMMs (BK=32, 4-deep LDS circular buffer, 1 barrier +
// 1 counted vmcnt per K-tile, prefetch distance 3).
//
//   s_q = relu(q @ W1^T), s_p = relu(p @ W2^T)   [gemm256_dp, 256^2 tile]
//   s   = s_q @ s_p^T (batched)                  [gemm128s_dp, hi+lo A terms]
//   wp  = softmax_n(s), wq = softmax_m(s^T)      [row + column softmax]
//   out_q = wp @ p, out_p = wq @ q               [gemm256_dp]
//
// fp16 operands in plain tiled layout: tile t = (r>>7)*ktiles + (k>>6),
// elem (r&127)*64 + (k&63). Staging gathers 16B/lane from global into
// linear LDS [256|128 rows][32 k] via global_load_lds (BK=32 rows stride
// 64B -> frag ds_read_b128 is naturally 2-way = conflict-free).
//
// Workspace (84 MiB):
//   [0,4)  W1h|W2h   [4,20) qh  [20,36) ph
//   [36,52) sqh  [52,68) sph  [68,84) sql
//   after proj:    s fp32 over [4,20)
//   after scores:  pT [52,68) qT [68,84) (over sph/sql), wp [36,44) wq [44,52)

#define AS1 __attribute__((address_space(1)))
#define AS3 __attribute__((address_space(3)))

typedef _Float16 f16x8 __attribute__((ext_vector_type(8)));
typedef float f32x4 __attribute__((ext_vector_type(4)));

// ---- fp32 -> fp16 tiled, q then p (rows 0..16383, row length 1024) --------
__global__ __launch_bounds__(256) void prep_x(
    const float* __restrict__ q, const float* __restrict__ p,
    _Float16* __restrict__ dst)
{
  long g = (long)blockIdx.x * 256 + threadIdx.x;   // one thread per 8 elems
  int rg = (int)(g >> 7);
  int c8 = ((int)g & 127) << 3;
  const float* srow = (rg < 8192) ? (q + (long)rg * 1024 + c8)
                                  : (p + (long)(rg - 8192) * 1024 + c8);
  const float4* s4 = (const float4*)srow;
  float4 f0 = s4[0], f1 = s4[1];
  f16x8 hh;
  hh[0]=(_Float16)f0.x; hh[1]=(_Float16)f0.y; hh[2]=(_Float16)f0.z; hh[3]=(_Float16)f0.w;
  hh[4]=(_Float16)f1.x; hh[5]=(_Float16)f1.y; hh[6]=(_Float16)f1.z; hh[7]=(_Float16)f1.w;
  long off = ((long)(rg >> 7) * 16 + (c8 >> 6)) * 8192 + (long)(rg & 127) * 64 + (c8 & 63);
  *(f16x8*)(dst + off) = hh;
}

// ---- fp32 -> fp16 tiled, W1 then W2 (rows 0..2047) ------------------------
__global__ __launch_bounds__(256) void prep_w(
    const float* __restrict__ W1, const float* __restrict__ W2,
    _Float16* __restrict__ dst)
{
  long g = (long)blockIdx.x * 256 + threadIdx.x;
  int rg = (int)(g >> 7);
  int c8 = ((int)g & 127) << 3;
  const float* srow = (rg < 1024) ? (W1 + (long)rg * 1024 + c8)
                                  : (W2 + (long)(rg - 1024) * 1024 + c8);
  const float4* s4 = (const float4*)srow;
  float4 f0 = s4[0], f1 = s4[1];
  f16x8 hh;
  hh[0]=(_Float16)f0.x; hh[1]=(_Float16)f0.y; hh[2]=(_Float16)f0.z; hh[3]=(_Float16)f0.w;
  hh[4]=(_Float16)f1.x; hh[5]=(_Float16)f1.y; hh[6]=(_Float16)f1.z; hh[7]=(_Float16)f1.w;
  long off = ((long)(rg >> 7) * 16 + (c8 >> 6)) * 8192 + (long)(rg & 127) * 64 + (c8 & 63);
  *(f16x8*)(dst + off) = hh;
}

// ---- batched transpose fp32 -> fp16 tiled: p->pT then q->qT ---------------
// src batch [512 m][1024 v] -> dst batch [1024 v][512 m] tiled (ktiles=8)
__global__ __launch_bounds__(256) void prep_xT(
    const float* __restrict__ q, const float* __restrict__ p,
    _Float16* __restrict__ dstT)
{
  __shared__ float t[64][65];
  const int x = blockIdx.x, y = blockIdx.y, zz = blockIdx.z;
  const float* src = (zz < 16) ? (p + (long)zz * 524288)
                               : (q + (long)(zz - 16) * 524288);
  const int tid = threadIdx.x;
  for (int it = 0; it < 4; ++it) {
    int id = it * 256 + tid;
    int rr = id >> 4, cc = (id & 15) << 2;
    float4 f = *(const float4*)(src + (long)(y * 64 + rr) * 1024 + x * 64 + cc);
    t[rr][cc] = f.x; t[rr][cc + 1] = f.y; t[rr][cc + 2] = f.z; t[rr][cc + 3] = f.w;
  }
  __syncthreads();
  _Float16* db = dstT + (long)zz * 524288 + ((long)(x >> 1) * 8 + y) * 8192
               + (long)(x & 1) * 4096;
  for (int it = 0; it < 2; ++it) {
    int id = it * 256 + tid;
    int c = id >> 3, ch = id & 7;
    f16x8 hh;
#pragma unroll
    for (int i = 0; i < 8; ++i) hh[i] = (_Float16)t[ch * 8 + i][c];
    *(f16x8*)(db + (long)c * 64 + ch * 8) = hh;
  }
}

// ---- 256^2 deep-pipelined NT GEMM (1-term fp16) ---------------------------
// BK=32, 4-deep circular buffer, vmcnt(8) + 1 barrier per K-tile.
// OUTMODE 0: fp32 row-major (cSplit); OUTMODE 2: fp16 tiled hi (+lo bz<loZMax)
template<bool RELU, int OUTMODE>
__global__ __launch_bounds__(512, 2) void gemm256_dp(
    const _Float16* __restrict__ A, const _Float16* __restrict__ B,
    float* __restrict__ Cf, _Float16* __restrict__ Ch, _Float16* __restrict__ Cl,
    const int loZMax, const int ktiles, const int ldc,
    const long aBatchTiles, const long bBatchTiles, const long cBatchElems,
    const int cTilesRow, const long cOff0, const long cOff1, const int cSplit)
{
  __shared__ _Float16 sA[4][8192];   // 256 rows x 32 k per buf
  __shared__ _Float16 sB[4][8192];

  const int gx = gridDim.x, gy = gridDim.y;
  long nwg = (long)gx * gy * gridDim.z;
  long bid = blockIdx.x + (long)gx * (blockIdx.y + (long)gy * blockIdx.z);
  long chunk = nwg >> 3;
  long o = (bid & 7) * chunk + (bid >> 3);
  const int bx = (int)(o % gx);
  const int by = (int)((o / gx) % gy);
  const int bz = (int)(o / ((long)gx * gy));

  const int tid = threadIdx.x;
  const int lane = tid & 63, w = tid >> 6;
  const int wm = w >> 2, wn = w & 3;            // 2 x 4 wave grid, tile 128x64
  const int lrow = lane & 15, kg = lane >> 4;

  const long aT0 = (long)bz * aBatchTiles + (long)(by * 2) * ktiles;
  const long bT0 = (long)bz * bBatchTiles + (long)(bx * 2) * ktiles;
  const int NKT = ktiles * 2;

  const int srow = tid >> 2;                     // 0..127
  const int scol = (tid & 3) << 3;               // elem in 32-k window

  auto stage = [&](int kt) {
    const int buf = kt & 3;
    const int ktg = kt >> 1;
    const int ks = (kt & 1) << 5;
    const long ea = ((aT0 + ktg) << 13) + (long)srow * 64 + ks + scol;
    const long eb = ((bT0 + ktg) << 13) + (long)srow * 64 + ks + scol;
#pragma unroll
    for (int g = 0; g < 2; ++g) {
      __builtin_amdgcn_global_load_lds(
          (const AS1 void*)(A + ea + ((long)(g * ktiles) << 13)),
          (AS3 void*)(&sA[buf][g * 4096 + w * 512]), 16, 0, 0);
      __builtin_amdgcn_global_load_lds(
          (const AS1 void*)(B + eb + ((long)(g * ktiles) << 13)),
          (AS3 void*)(&sB[buf][g * 4096 + w * 512]), 16, 0, 0);
    }
  };

  const char* aF = (const char*)&sA[0][0] + (wm * 128 + lrow) * 64 + kg * 16;
  const char* bF = (const char*)&sB[0][0] + (wn * 64 + lrow) * 64 + kg * 16;

  f32x4 acc[8][4] = {};

  stage(0); stage(1); stage(2);

  for (int kt = 0; kt < NKT; ++kt) {
    asm volatile("s_waitcnt vmcnt(8)" ::: "memory");   // tile kt staged (2 ahead in flight)
    __builtin_amdgcn_s_barrier();
    __builtin_amdgcn_sched_barrier(0);
    const int bo = (kt & 3) * 16384;
    f16x8 a0[4], b[4];
#pragma unroll
    for (int i = 0; i < 4; ++i) a0[i] = *(const f16x8*)(aF + bo + i * 1024);
#pragma unroll
    for (int i = 0; i < 4; ++i) b[i] = *(const f16x8*)(bF + bo + i * 1024);
    if (kt + 3 < NKT) stage(kt + 3);
    f16x8 a1[4];
#pragma unroll
    for (int i = 0; i < 4; ++i) a1[i] = *(const f16x8*)(aF + bo + 4096 + i * 1024);
    __builtin_amdgcn_s_setprio(1);
#pragma unroll
    for (int mi = 0; mi < 4; ++mi)
#pragma unroll
      for (int ni = 0; ni < 4; ++ni)
        acc[mi][ni] = __builtin_amdgcn_mfma_f32_16x16x32_f16(a0[mi], b[ni], acc[mi][ni], 0, 0, 0);
#pragma unroll
    for (int mi = 0; mi < 4; ++mi)
#pragma unroll
      for (int ni = 0; ni < 4; ++ni)
        acc[4 + mi][ni] = __builtin_amdgcn_mfma_f32_16x16x32_f16(a1[mi], b[ni], acc[4 + mi][ni], 0, 0, 0);
    __builtin_amdgcn_s_setprio(0);
  }

  const int rb = by * 256 + wm * 128 + (kg << 2);
  const int cb = bx * 256 + wn * 64 + lrow;
  if (OUTMODE == 0) {
    long cbase = cSplit ? (bz < 16 ? cOff0 + (long)bz * cBatchElems
                                   : cOff1 + (long)(bz - 16) * cBatchElems)
                        : (long)bz * cBatchElems;
    float* Cb = Cf + cbase;
#pragma unroll
    for (int mi = 0; mi < 8; ++mi)
#pragma unroll
      for (int ni = 0; ni < 4; ++ni)
#pragma unroll
        for (int r2 = 0; r2 < 4; ++r2)
          Cb[(long)(rb + mi * 16 + r2) * ldc + cb + ni * 16] = acc[mi][ni][r2];
  } else {
    const bool wlo = (bz < loZMax);
#pragma unroll
    for (int mi = 0; mi < 8; ++mi)
#pragma unroll
      for (int ni = 0; ni < 4; ++ni)
#pragma unroll
        for (int r2 = 0; r2 < 4; ++r2) {
          int r = rb + mi * 16 + r2, c = cb + ni * 16;
          float x = acc[mi][ni][r2];
          if (RELU) x = fmaxf(x, 0.0f);
          long idx = (long)bz * cBatchElems
                   + ((long)((r >> 7) * cTilesRow + (c >> 6)) << 13)
                   + ((long)(r & 127) << 6) + (c & 63);
          _Float16 hv = (_Float16)x;
          Ch[idx] = hv;
          if (wlo) Cl[idx] = (_Float16)(x - (float)hv);
        }
  }
}

// ---- 128^2 deep-pipelined NT GEMM, 2-term A (scores) ----------------------
__global__ __launch_bounds__(512, 2) void gemm128s_dp(
    const _Float16* __restrict__ Ah, const _Float16* __restrict__ Al,
    const _Float16* __restrict__ B, float* __restrict__ Cf,
    const int ktiles, const int ldc,
    const long aBatchTiles, const long bBatchTiles, const long cBatchElems)
{
  __shared__ _Float16 sAh[4][4096];   // 128 rows x 32 k
  __shared__ _Float16 sAl[4][4096];
  __shared__ _Float16 sBv[4][4096];

  const int gx = gridDim.x, gy = gridDim.y;
  long nwg = (long)gx * gy * gridDim.z;
  long bid = blockIdx.x + (long)gx * (blockIdx.y + (long)gy * blockIdx.z);
  long chunk = nwg >> 3;
  long o = (bid & 7) * chunk + (bid >> 3);
  const int bx = (int)(o % gx);
  const int by = (int)((o / gx) % gy);
  const int bz = (int)(o / ((long)gx * gy));

  const int tid = threadIdx.x;
  const int lane = tid & 63, w = tid >> 6;
  const int wm = w >> 2, wn = w & 3;            // 2 x 4 wave grid, tile 64x32
  const int lrow = lane & 15, kg = lane >> 4;

  const long aT0 = (long)bz * aBatchTiles + (long)by * ktiles;
  const long bT0 = (long)bz * bBatchTiles + (long)bx * ktiles;
  const int NKT = ktiles * 2;

  const int srow = tid >> 2;
  const int scol = (tid & 3) << 3;

  auto stage = [&](int kt) {
    const int buf = kt & 3;
    const int ktg = kt >> 1;
    const int ks = (kt & 1) << 5;
    const long ea = ((aT0 + ktg) << 13) + (long)srow * 64 + ks + scol;
    const long eb = ((bT0 + ktg) << 13) + (long)srow * 64 + ks + scol;
    __builtin_amdgcn_global_load_lds((const AS1 void*)(Ah + ea),
        (AS3 void*)(&sAh[buf][w * 512]), 16, 0, 0);
    __builtin_amdgcn_global_load_lds((const AS1 void*)(Al + ea),
        (AS3 void*)(&sAl[buf][w * 512]), 16, 0, 0);
    __builtin_amdgcn_global_load_lds((const AS1 void*)(B + eb),
        (AS3 void*)(&sBv[buf][w * 512]), 16, 0, 0);
  };

  const char* aFh = (const char*)&sAh[0][0] + (wm * 64 + lrow) * 64 + kg * 16;
  const char* aFl = (const char*)&sAl[0][0] + (wm * 64 + lrow) * 64 + kg * 16;
  const char* bF  = (const char*)&sBv[0][0] + (wn * 32 + lrow) * 64 + kg * 16;

  f32x4 acc[4][2] = {};

  stage(0); stage(1); stage(2);

  for (int kt = 0; kt < NKT; ++kt) {
    asm volatile("s_waitcnt vmcnt(6)" ::: "memory");
    __builtin_amdgcn_s_barrier();
    __builtin_amdgcn_sched_barrier(0);
    const int bo = (kt & 3) * 8192;
    f16x8 ah[4], al[4], bb[2];
#pragma unroll
    for (int i = 0; i < 4; ++i) ah[i] = *(const f16x8*)(aFh + bo + i * 1024);
#pragma unroll
    for (int i = 0; i < 2; ++i) bb[i] = *(const f16x8*)(bF + bo + i * 1024);
#pragma unroll
    for (int i = 0; i < 4; ++i) al[i] = *(const f16x8*)(aFl + bo + i * 1024);
    if (kt + 3 < NKT) stage(kt + 3);
    __builtin_amdgcn_s_setprio(1);
#pragma unroll
    for (int mi = 0; mi < 4; ++mi)
#pragma unroll
      for (int ni = 0; ni < 2; ++ni) {
        acc[mi][ni] = __builtin_amdgcn_mfma_f32_16x16x32_f16(ah[mi], bb[ni], acc[mi][ni], 0, 0, 0);
        acc[mi][ni] = __builtin_amdgcn_mfma_f32_16x16x32_f16(al[mi], bb[ni], acc[mi][ni], 0, 0, 0);
      }
    __builtin_amdgcn_s_setprio(0);
  }

  float* Cb = Cf + (long)bz * cBatchElems;
  const int rb = by * 128 + wm * 64 + (kg << 2);
  const int cb = bx * 128 + wn * 32 + lrow;
#pragma unroll
  for (int mi = 0; mi < 4; ++mi)
#pragma unroll
    for (int ni = 0; ni < 2; ++ni)
#pragma unroll
      for (int r2 = 0; r2 < 4; ++r2)
        Cb[(long)(rb + mi * 16 + r2) * ldc + cb + ni * 16] = acc[mi][ni][r2];
}

// ---- row softmax (512 cols) -> fp16 tiled wp ------------------------------
__global__ __launch_bounds__(256) void softmax_row(
    const float* __restrict__ S, const int* __restrict__ mask, _Float16* __restrict__ W)
{
  const int row = blockIdx.x, b = row >> 9, m = row & 511;
  const float* Sr = S + (long)row * 512;
  const int* mr = mask + (long)b * 512;
  const int tid = threadIdx.x;
  const int lane = tid & 63, wave = tid >> 6;
  __shared__ float red[4];

  float v0 = mr[tid] ? Sr[tid] : -1e30f;
  float v1 = mr[tid + 256] ? Sr[tid + 256] : -1e30f;
  float mx = fmaxf(v0, v1);
#pragma unroll
  for (int of = 32; of >= 1; of >>= 1) mx = fmaxf(mx, __shfl_xor(mx, of, 64));
  if (lane == 0) red[wave] = mx;
  __syncthreads();
  mx = fmaxf(fmaxf(red[0], red[1]), fmaxf(red[2], red[3]));
  __syncthreads();
  float e0 = __expf(v0 - mx), e1 = __expf(v1 - mx);
  float sm = e0 + e1;
#pragma unroll
  for (int of = 32; of >= 1; of >>= 1) sm += __shfl_xor(sm, of, 64);
  if (lane == 0) red[wave] = sm;
  __syncthreads();
  float inv = 1.0f / (red[0] + red[1] + red[2] + red[3]);

  long base = (long)b * 262144 + (long)(m >> 7) * 65536 + (long)(m & 127) * 64;
  int n1 = tid + 256;
  W[base + (long)(tid >> 6) * 8192 + (tid & 63)] = (_Float16)(e0 * inv);
  W[base + (long)(n1 >> 6) * 8192 + (n1 & 63)] = (_Float16)(e1 * inv);
}

// ---- column softmax: wq[b][n][m] = softmax_m(s[b][m][n]) ------------------
__global__ __launch_bounds__(256) void softmax_col(
    const float* __restrict__ S, const int* __restrict__ mask, _Float16* __restrict__ W)
{
  __shared__ float ldsT[32][513];
  const int n0 = blockIdx.x * 32, b = blockIdx.y;
  const float* Sb = S + (long)b * 262144;
  const int* mr = mask + (long)b * 512;
  const int tid = threadIdx.x;
  const int lane = tid & 63, w = tid >> 6;

  for (int it = 0; it < 64; ++it) {
    int m = it * 8 + (tid >> 5);
    int c = tid & 31;
    float v = mr[m] ? Sb[(long)m * 512 + n0 + c] : -1e30f;
    ldsT[c][m] = v;
  }
  __syncthreads();

#pragma unroll
  for (int cc = 0; cc < 8; ++cc) {
    int col = w * 8 + cc;
    float v[8];
#pragma unroll
    for (int j = 0; j < 8; ++j) v[j] = ldsT[col][lane + 64 * j];
    float mx = v[0];
#pragma unroll
    for (int j = 1; j < 8; ++j) mx = fmaxf(mx, v[j]);
#pragma unroll
    for (int of = 32; of >= 1; of >>= 1) mx = fmaxf(mx, __shfl_xor(mx, of, 64));
    float e[8], sm = 0.0f;
#pragma unroll
    for (int j = 0; j < 8; ++j) { e[j] = __expf(v[j] - mx); sm += e[j]; }
#pragma unroll
    for (int of = 32; of >= 1; of >>= 1) sm += __shfl_xor(sm, of, 64);
    float inv = 1.0f / sm;
    int n = n0 + col;
    long bw = (long)b * 262144 + (long)(n >> 7) * 65536 + (long)(n & 127) * 64;
#pragma unroll
    for (int j = 0; j < 8; ++j)
      W[bw + (long)j * 8192 + lane] = (_Float16)(e[j] * inv);
  }
}

extern "C" void kernel_launch(void* const* d_in, const int* in_sizes, int n_in,
                              void* d_out, int out_size, void* d_ws, size_t ws_size,
                              hipStream_t stream) {
  const float* q = (const float*)d_in[0];
  const float* p = (const float*)d_in[1];
  const int* q_mask = (const int*)d_in[2];
  const int* p_mask = (const int*)d_in[3];
  const float* W1 = (const float*)d_in[4];
  const float* W2 = (const float*)d_in[5];
  float* out = (float*)d_out;   // [out_p | out_q]

  char* ws = (char*)d_ws;
  const size_t MB = 1048576;
  _Float16* W1h = (_Float16*)(ws + 0 * MB);    // W2h contiguous at +2MB
  _Float16* qh  = (_Float16*)(ws + 4 * MB);    // ph contiguous at +16MB
  _Float16* sqh = (_Float16*)(ws + 36 * MB);   // sph contiguous at +16MB
  _Float16* sph = (_Float16*)(ws + 52 * MB);
  _Float16* sql = (_Float16*)(ws + 68 * MB);
  float*    s   = (float*)(ws + 4 * MB);       // over qh/ph (dead after proj)
  _Float16* wp  = (_Float16*)(ws + 36 * MB);   // over sqh; wq contiguous
  _Float16* wq  = (_Float16*)(ws + 44 * MB);
  _Float16* pT  = (_Float16*)(ws + 52 * MB);   // over sph; qT contiguous
  // qT at 68MB over sql

  dim3 blk(256);

  // 1) fp16 conversions into plain tiles
  prep_w<<<1024, blk, 0, stream>>>(W1, W2, W1h);
  prep_x<<<8192, blk, 0, stream>>>(q, p, qh);

  // 2) merged projections (z=0: q@W1 -> sqh+sql, z=1: p@W2 -> sph)
  gemm256_dp<true, 2><<<dim3(4, 32, 2), dim3(512), 0, stream>>>(
      qh, W1h, nullptr, sqh, sql,
      /*loZMax=*/1, /*ktiles=*/16, /*ldc=*/0,
      /*aBatchTiles=*/1024, /*bBatchTiles=*/128, /*cBatchElems=*/8388608L,
      /*cTilesRow=*/16, 0, 0, 0);

  // 3) scores: s[b] = s_q[b] @ s_p[b]^T  (A = hi + lo, shared B)
  gemm128s_dp<<<dim3(4, 4, 16), dim3(512), 0, stream>>>(
      sqh, sql, sph, s, /*ktiles=*/16, /*ldc=*/512, 64, 64, 262144L);

  // 4) transposed fp16 copies of p, q (over dead sph/sql)
  prep_xT<<<dim3(16, 8, 32), blk, 0, stream>>>(q, p, pT);

  // 5) softmaxes
  softmax_row<<<8192, blk, 0, stream>>>(s, p_mask, wp);
  softmax_col<<<dim3(16, 16), blk, 0, stream>>>(s, q_mask, wq);

  // 6) merged outputs: z<16: out_q = wp@pT^T; z>=16: out_p = wq@qT^T
  gemm256_dp<false, 0><<<dim3(4, 2, 32), dim3(512), 0, stream>>>(
      wp, pT, out, nullptr, nullptr,
      0, /*ktiles=*/8, /*ldc=*/1024,
      /*aBatchTiles=*/32, /*bBatchTiles=*/64, /*cBatchElems=*/524288L,
      0, /*cOff0=*/8388608L, /*cOff1=*/0L, /*cSplit=*/1);
}